// Round 1
// 2959.171 us; speedup vs baseline: 1.0489x; 1.0489x over previous
//
#include <hip/hip_runtime.h>
#include <stdint.h>

// Problem constants (fixed by setup_inputs)
constexpr int Bn = 32, Cc = 24, Hh = 28, Ww = 28;
constexpr int OHt = 24, OWt = 24;           // output spatial
constexpr int CF = 600, HN = 128, TT = 96;  // channels-folded, hidden, spikes
constexpr int NPIX = OHt * OWt;             // 576
constexpr int NSAMP = Bn * TT * NPIX;       // 1,769,472
constexpr int NLOG = Bn * Cc * Hh * Ww;     // 602,112

// ---- JAX threefry2x32, key(42) -> (0, 42), partitionable counter mode ----
// out32(i) = x0' ^ x1' of threefry2x32((0,42), (hi32(i)=0, lo32(i)=i))
__device__ __forceinline__ uint32_t threefry_0_42(uint32_t x1) {
  const uint32_t ks1 = 42u, ks2 = 0x1BD11BF0u;  // 0x1BD11BDA ^ 0 ^ 42
  uint32_t x0 = 0u;        // x0 += ks0 (=0)
  x1 += ks1;
#define TF_RND(r) { x0 += x1; x1 = (x1 << (r)) | (x1 >> (32 - (r))); x1 ^= x0; }
  TF_RND(13) TF_RND(15) TF_RND(26) TF_RND(6)
  x0 += ks1; x1 += ks2 + 1u;
  TF_RND(17) TF_RND(29) TF_RND(16) TF_RND(24)
  x0 += ks2; x1 += 0u + 2u;
  TF_RND(13) TF_RND(15) TF_RND(26) TF_RND(6)
  x0 += 0u; x1 += ks1 + 3u;
  TF_RND(17) TF_RND(29) TF_RND(16) TF_RND(24)
  x0 += ks1; x1 += ks2 + 4u;
  TF_RND(13) TF_RND(15) TF_RND(26) TF_RND(6)
  x0 += ks2; x1 += 0u + 5u;
#undef TF_RND
  return x0 ^ x1;
}

__global__ __launch_bounds__(256) void k_log(const float* __restrict__ in,
                                             float* __restrict__ lp) {
  int i = blockIdx.x * 256 + threadIdx.x;
  if (i < NLOG) lp[i] = logf(in[i]);
}

// One thread per sample (b,t,x,y): argmax over 600 gumbel+logit, first-max wins.
//
// Fast path: v_hat = lp - ln2*log2(-log2(u))  (two hw v_log_f32 + 1 fma)
//   approximates v - C  (C = -ln(ln2) = 0.36651292) to ~1e-5.
// Exact path (rare, gated): the ocml logf chain, bit-identical to the
//   reference / previous passing kernel, decides every winner. Gate admits a
//   guaranteed superset: margin EPSG >> approx error, plus a near-1 guard
//   (u >= 1 - 2^-12) where hw log2 relative accuracy could degrade.
__global__ __launch_bounds__(256) void k_sample(const float* __restrict__ logp,
                                                int* __restrict__ spikes) {
  int sid = blockIdx.x * 256 + threadIdx.x;
  if (sid >= NSAMP) return;
  int y = sid % OWt;
  int x = (sid / OWt) % OHt;
  int b = sid / (NPIX * TT);
  uint32_t base = (uint32_t)sid * 600u;  // flat gumbel index base (< 2^32)
  const float* lpb = logp + (b * Cc) * (Hh * Ww) + x * Ww + y;

  constexpr float LN2 = 0.6931471805599453f;
  constexpr float NEG_LN_LN2 = 0.36651292058166433f;  // C = -ln(ln 2)
  constexpr float EPSG = 0.03125f;                    // >> |v_hat + C - v|
  constexpr float UCLOSE = 0.999755859375f;           // 1 - 2^-12

  float best = -1e30f;
  int bi = 0;
  float gate = -3.0e38f;  // tracks best - (EPSG + NEG_LN_LN2)
  int cf = 0;
  for (int c = 0; c < Cc; ++c) {
    const float* lpc = lpb + c * (Hh * Ww);
    for (int ki = 0; ki < 5; ++ki) {
      #pragma unroll
      for (int kj = 0; kj < 5; ++kj) {
        uint32_t bits = threefry_0_42(base + (uint32_t)cf);
        float f = __uint_as_float((bits >> 9) | 0x3f800000u) - 1.0f;
        float u = (f == 0.0f) ? 1.17549435e-38f : f;  // max(tiny, f)
        float lp = lpc[ki * Ww + kj];
        float t = __log2f(u);    // v_log_f32, t < 0 always (u < 1)
        float n = __log2f(-t);   // v_log_f32
        float vhat = __builtin_fmaf(-LN2, n, lp);  // ~ v - C
        if (vhat > gate || u >= UCLOSE) {
          // exact, bit-identical to reference: g = -log(-log(u)); v = g + lp
          float l1 = logf(u);
          float g = -logf(-l1);
          float v = g + lp;
          if (v > best) {
            best = v;
            bi = cf;
            gate = v - (EPSG + NEG_LN_LN2);
          }
        }
        ++cf;
      }
    }
  }
  spikes[sid] = bi;
}

// One wave per pixel, 2 neurons per lane; 96 sequential normalized updates.
__global__ __launch_bounds__(256) void k_recur(
    const int* __restrict__ spikes, const float* __restrict__ weights,
    const float* __restrict__ eps_xy, const float* __restrict__ eps_t,
    const float* __restrict__ eps0p, const float* __restrict__ h_init,
    float* __restrict__ out) {
  int wid = blockIdx.x * 4 + (threadIdx.x >> 6);  // pixel id in [0, 18432)
  int lane = threadIdx.x & 63;
  int y = wid % OWt;
  int x = (wid / OWt) % OHt;
  int b = wid / NPIX;
  float g0 = h_init[lane];
  float g1 = h_init[lane + 64];
  float e0 = eps0p[0];
  const int* sp = spikes + (b * TT) * NPIX + x * OWt + y;
  const float* ex = eps_xy + (x * OWt + y) * 25;
  for (int t = 0; t < TT; ++t) {
    int s = sp[t * NPIX];  // wave-uniform
    const float* wr = weights + s * HN;
    float wg0 = wr[lane] * g0;
    float wg1 = wr[lane + 64] * g1;
    float sum = wg0 + wg1;
    #pragma unroll
    for (int off = 32; off > 0; off >>= 1) sum += __shfl_xor(sum, off, 64);
    float es = ex[s % 25] * (eps_t[t] * e0);  // eps * (et * eps0)
    float factor = es / sum;
    if (!__builtin_isfinite(factor)) factor = 0.0f;  // nan_to_num
    float d = 1.0f + es;
    g0 = (g0 + wg0 * factor) / d;
    g1 = (g1 + wg1 * factor) / d;
  }
  out[((b * HN + lane) * OHt + x) * OWt + y] = g0;
  out[((b * HN + lane + 64) * OHt + x) * OWt + y] = g1;
}

extern "C" void kernel_launch(void* const* d_in, const int* in_sizes, int n_in,
                              void* d_out, int out_size, void* d_ws, size_t ws_size,
                              hipStream_t stream) {
  const float* input   = (const float*)d_in[0];
  const float* eps_xy  = (const float*)d_in[1];
  const float* eps0    = (const float*)d_in[2];
  const float* eps_t   = (const float*)d_in[3];
  const float* weights = (const float*)d_in[4];
  const float* h_init  = (const float*)d_in[5];
  // d_in[6] = number_of_spikes (=96, hardcoded)

  float* logp = (float*)d_ws;                                // 602,112 f32
  int* spikes = (int*)((char*)d_ws + NLOG * sizeof(float));  // 1,769,472 i32

  k_log<<<(NLOG + 255) / 256, 256, 0, stream>>>(input, logp);
  k_sample<<<NSAMP / 256, 256, 0, stream>>>(logp, spikes);
  k_recur<<<(Bn * NPIX) / 4, 256, 0, stream>>>(spikes, weights, eps_xy, eps_t,
                                               eps0, h_init, (float*)d_out);
}

// Round 2
// 2430.916 us; speedup vs baseline: 1.2768x; 1.2173x over previous
//
#include <hip/hip_runtime.h>
#include <stdint.h>

// Problem constants (fixed by setup_inputs)
constexpr int Bn = 32, Cc = 24, Hh = 28, Ww = 28;
constexpr int OHt = 24, OWt = 24;           // output spatial
constexpr int CF = 600, HN = 128, TT = 96;  // channels-folded, hidden, spikes
constexpr int NPIX = OHt * OWt;             // 576
constexpr int NSAMP = Bn * TT * NPIX;       // 1,769,472
constexpr int NLOG = Bn * Cc * Hh * Ww;     // 602,112

// ---- JAX threefry2x32, key(42) -> (0, 42), partitionable counter mode ----
__device__ __forceinline__ uint32_t threefry_0_42(uint32_t x1) {
  const uint32_t ks1 = 42u, ks2 = 0x1BD11BF0u;  // 0x1BD11BDA ^ 0 ^ 42
  uint32_t x0 = 0u;
  x1 += ks1;
#define TF_RND(r) { x0 += x1; x1 = (x1 << (r)) | (x1 >> (32 - (r))); x1 ^= x0; }
  TF_RND(13) TF_RND(15) TF_RND(26) TF_RND(6)
  x0 += ks1; x1 += ks2 + 1u;
  TF_RND(17) TF_RND(29) TF_RND(16) TF_RND(24)
  x0 += ks2; x1 += 0u + 2u;
  TF_RND(13) TF_RND(15) TF_RND(26) TF_RND(6)
  x0 += 0u; x1 += ks1 + 3u;
  TF_RND(17) TF_RND(29) TF_RND(16) TF_RND(24)
  x0 += ks1; x1 += ks2 + 4u;
  TF_RND(13) TF_RND(15) TF_RND(26) TF_RND(6)
  x0 += ks2; x1 += 0u + 5u;
#undef TF_RND
  return x0 ^ x1;
}

__global__ __launch_bounds__(256) void k_log(const float* __restrict__ in,
                                             float* __restrict__ lp) {
  int i = blockIdx.x * 256 + threadIdx.x;
  if (i < NLOG) lp[i] = logf(in[i]);
}

// Per-(b,pixel) max of the 600 candidate log-probs (for the bits-gate bound).
__global__ __launch_bounds__(256) void k_lpmax(const float* __restrict__ lp,
                                               float* __restrict__ out) {
  int pid = blockIdx.x * 256 + threadIdx.x;  // (b, x, y)
  if (pid >= Bn * NPIX) return;
  int y = pid % OWt;
  int x = (pid / OWt) % OHt;
  int b = pid / NPIX;
  const float* p = lp + (b * Cc) * (Hh * Ww) + x * Ww + y;
  float m = -3.0e38f;
  for (int c = 0; c < Cc; ++c) {
    const float* pc = p + c * (Hh * Ww);
    #pragma unroll
    for (int ki = 0; ki < 5; ++ki)
      #pragma unroll
      for (int kj = 0; kj < 5; ++kj) m = fmaxf(m, pc[ki * Ww + kj]);
  }
  out[pid] = m;
}

// Conservative bits-threshold: admit every u whose exact (ocml) value could
// beat `best`. bgap = best - lpmax. Chain with one-sided margins:
//   G3 = bgap - 2^-8  (covers f32 add slop + ocml logf eval error, generously)
//   U_lo <= exp(-exp(-G3)) via +/- 2^-16 relative slop around each __expf
//   key threshold - 64 on the integer conversion.
// Stale thr (from an older, smaller best) is still sound.
__device__ __forceinline__ uint32_t mkthr(float bgap) {
  float g3 = bgap - 0.00390625f;
  float e1 = __expf(-g3) * 1.0000153f;   // >= exp(-g3)
  float ul = __expf(-e1) * 0.9999847f;   // <= exp(-e1) <= inverse
  int kt = (int)(ul * 8388608.0f) - 64;
  return (kt < 1) ? 0u : ((uint32_t)kt << 9);
}

// Exact path (rare): bit-identical to the reference/previous passing kernel.
__device__ __forceinline__ void upd(uint32_t bits, float lp, float lpmax,
                                    int cf, float& best, int& bi,
                                    uint32_t& thr) {
  if (bits < thr) return;                       // level-1 gate: 1 compare
  uint32_t key = bits >> 9;
  float f = __uint_as_float(key | 0x3f800000u) - 1.0f;
  float u = (f == 0.0f) ? 1.17549435e-38f : f;  // max(tiny, f)
  float l1 = logf(u);
  float v = -logf(-l1) + lp;                    // g + lp, exact ocml chain
  if (v > best) {                               // strict >: first-max-wins
    best = v;
    bi = cf;
    thr = mkthr(v - lpmax);
  }
}

// One thread per t-PAIR: samples (b,t,x,y) and (b,t+48,x,y) share the lp
// stream, lpmax, and loop overhead; two independent threefry chains give
// 2x ILP on the serial ARX dependency chain.
__global__ __launch_bounds__(256) void k_sample(const float* __restrict__ logp,
                                                const float* __restrict__ lpmaxa,
                                                int* __restrict__ spikes) {
  int tid = blockIdx.x * 256 + threadIdx.x;  // [0, NSAMP/2)
  int y = tid % OWt;
  int x = (tid / OWt) % OHt;
  int t = (tid / NPIX) % 48;
  int b = tid / (NPIX * 48);
  int sid1 = ((b * TT + t) * OHt + x) * OWt + y;
  int sid2 = sid1 + 48 * NPIX;
  uint32_t base1 = (uint32_t)sid1 * 600u;
  uint32_t base2 = (uint32_t)sid2 * 600u;
  const float* lpb = logp + (b * Cc) * (Hh * Ww) + x * Ww + y;
  float lpmax = lpmaxa[(b * OHt + x) * OWt + y];
  float best1 = -1e30f, best2 = -1e30f;
  int bi1 = 0, bi2 = 0;
  uint32_t thr1 = 0u, thr2 = 0u;  // 0 => admit-all (warm-up)
  int cf = 0;
  #pragma unroll 1
  for (int c = 0; c < Cc; ++c) {
    const float* lpc = lpb + c * (Hh * Ww);
    #pragma unroll 1
    for (int ki = 0; ki < 5; ++ki) {
      #pragma unroll
      for (int kj = 0; kj < 5; ++kj) {
        float lp = lpc[ki * Ww + kj];
        uint32_t bits1 = threefry_0_42(base1 + (uint32_t)cf);
        uint32_t bits2 = threefry_0_42(base2 + (uint32_t)cf);
        upd(bits1, lp, lpmax, cf, best1, bi1, thr1);
        upd(bits2, lp, lpmax, cf, best2, bi2, thr2);
        ++cf;
      }
    }
  }
  spikes[sid1] = bi1;
  spikes[sid2] = bi2;
}

// One wave per pixel, 2 neurons per lane; 96 sequential normalized updates.
__global__ __launch_bounds__(256) void k_recur(
    const int* __restrict__ spikes, const float* __restrict__ weights,
    const float* __restrict__ eps_xy, const float* __restrict__ eps_t,
    const float* __restrict__ eps0p, const float* __restrict__ h_init,
    float* __restrict__ out) {
  int wid = blockIdx.x * 4 + (threadIdx.x >> 6);  // pixel id in [0, 18432)
  int lane = threadIdx.x & 63;
  int y = wid % OWt;
  int x = (wid / OWt) % OHt;
  int b = wid / NPIX;
  float g0 = h_init[lane];
  float g1 = h_init[lane + 64];
  float e0 = eps0p[0];
  const int* sp = spikes + (b * TT) * NPIX + x * OWt + y;
  const float* ex = eps_xy + (x * OWt + y) * 25;
  for (int t = 0; t < TT; ++t) {
    int s = sp[t * NPIX];  // wave-uniform
    const float* wr = weights + s * HN;
    float wg0 = wr[lane] * g0;
    float wg1 = wr[lane + 64] * g1;
    float sum = wg0 + wg1;
    #pragma unroll
    for (int off = 32; off > 0; off >>= 1) sum += __shfl_xor(sum, off, 64);
    float es = ex[s % 25] * (eps_t[t] * e0);  // eps * (et * eps0)
    float factor = es / sum;
    if (!__builtin_isfinite(factor)) factor = 0.0f;  // nan_to_num
    float d = 1.0f + es;
    g0 = (g0 + wg0 * factor) / d;
    g1 = (g1 + wg1 * factor) / d;
  }
  out[((b * HN + lane) * OHt + x) * OWt + y] = g0;
  out[((b * HN + lane + 64) * OHt + x) * OWt + y] = g1;
}

extern "C" void kernel_launch(void* const* d_in, const int* in_sizes, int n_in,
                              void* d_out, int out_size, void* d_ws, size_t ws_size,
                              hipStream_t stream) {
  const float* input   = (const float*)d_in[0];
  const float* eps_xy  = (const float*)d_in[1];
  const float* eps0    = (const float*)d_in[2];
  const float* eps_t   = (const float*)d_in[3];
  const float* weights = (const float*)d_in[4];
  const float* h_init  = (const float*)d_in[5];
  // d_in[6] = number_of_spikes (=96, hardcoded)

  float* logp = (float*)d_ws;                                // 602,112 f32
  int* spikes = (int*)((char*)d_ws + NLOG * sizeof(float));  // 1,769,472 i32
  // lpmax (18432 f32) staged in d_out; k_recur fully overwrites it later.
  float* lpmax = (float*)d_out;

  k_log<<<(NLOG + 255) / 256, 256, 0, stream>>>(input, logp);
  k_lpmax<<<(Bn * NPIX + 255) / 256, 256, 0, stream>>>(logp, lpmax);
  k_sample<<<(NSAMP / 2) / 256, 256, 0, stream>>>(logp, lpmax, spikes);
  k_recur<<<(Bn * NPIX) / 4, 256, 0, stream>>>(spikes, weights, eps_xy, eps_t,
                                               eps0, h_init, (float*)d_out);
}

// Round 3
// 2380.528 us; speedup vs baseline: 1.3038x; 1.0212x over previous
//
#include <hip/hip_runtime.h>
#include <stdint.h>

// Problem constants (fixed by setup_inputs)
constexpr int Bn = 32, Cc = 24, Hh = 28, Ww = 28;
constexpr int OHt = 24, OWt = 24;           // output spatial
constexpr int CF = 600, HN = 128, TT = 96;  // channels-folded, hidden, spikes
constexpr int NPIX = OHt * OWt;             // 576
constexpr int NSAMP = Bn * TT * NPIX;       // 1,769,472
constexpr int NLOG = Bn * Cc * Hh * Ww;     // 602,112

// ---- JAX threefry2x32, key(42) -> (0, 42), partitionable counter mode ----
// Caller pre-adds the ks1=42 key injection: pass x1 = counter + 42.
// Round 1 exploits x0_init = 0 (x0 += x1  ==>  x0 = x1).
__device__ __forceinline__ uint32_t threefry_0_42_pre(uint32_t x1) {
  const uint32_t ks1 = 42u, ks2 = 0x1BD11BF0u;  // 0x1BD11BDA ^ 0 ^ 42
  uint32_t x0 = x1;                                      // 0 + x1
  x1 = __builtin_rotateleft32(x1, 13) ^ x0;
  x0 += x1; x1 = __builtin_rotateleft32(x1, 15) ^ x0;
  x0 += x1; x1 = __builtin_rotateleft32(x1, 26) ^ x0;
  x0 += x1; x1 = __builtin_rotateleft32(x1,  6) ^ x0;
  x0 += ks1; x1 += ks2 + 1u;
  x0 += x1; x1 = __builtin_rotateleft32(x1, 17) ^ x0;
  x0 += x1; x1 = __builtin_rotateleft32(x1, 29) ^ x0;
  x0 += x1; x1 = __builtin_rotateleft32(x1, 16) ^ x0;
  x0 += x1; x1 = __builtin_rotateleft32(x1, 24) ^ x0;
  x0 += ks2; x1 += 2u;
  x0 += x1; x1 = __builtin_rotateleft32(x1, 13) ^ x0;
  x0 += x1; x1 = __builtin_rotateleft32(x1, 15) ^ x0;
  x0 += x1; x1 = __builtin_rotateleft32(x1, 26) ^ x0;
  x0 += x1; x1 = __builtin_rotateleft32(x1,  6) ^ x0;
  x1 += ks1 + 3u;
  x0 += x1; x1 = __builtin_rotateleft32(x1, 17) ^ x0;
  x0 += x1; x1 = __builtin_rotateleft32(x1, 29) ^ x0;
  x0 += x1; x1 = __builtin_rotateleft32(x1, 16) ^ x0;
  x0 += x1; x1 = __builtin_rotateleft32(x1, 24) ^ x0;
  x0 += ks1; x1 += ks2 + 4u;
  x0 += x1; x1 = __builtin_rotateleft32(x1, 13) ^ x0;
  x0 += x1; x1 = __builtin_rotateleft32(x1, 15) ^ x0;
  x0 += x1; x1 = __builtin_rotateleft32(x1, 26) ^ x0;
  x0 += x1; x1 = __builtin_rotateleft32(x1,  6) ^ x0;
  x0 += ks2; x1 += 5u;
  return x0 ^ x1;
}

__global__ __launch_bounds__(256) void k_log(const float* __restrict__ in,
                                             float* __restrict__ lp) {
  int i = blockIdx.x * 256 + threadIdx.x;
  if (i < NLOG) lp[i] = logf(in[i]);
}

// Per-(b,pixel) max of the 600 candidate log-probs (for the bits-gate bound).
__global__ __launch_bounds__(256) void k_lpmax(const float* __restrict__ lp,
                                               float* __restrict__ out) {
  int pid = blockIdx.x * 256 + threadIdx.x;  // (b, x, y)
  if (pid >= Bn * NPIX) return;
  int y = pid % OWt;
  int x = (pid / OWt) % OHt;
  int b = pid / NPIX;
  const float* p = lp + (b * Cc) * (Hh * Ww) + x * Ww + y;
  float m = -3.0e38f;
  for (int c = 0; c < Cc; ++c) {
    const float* pc = p + c * (Hh * Ww);
    #pragma unroll
    for (int ki = 0; ki < 5; ++ki)
      #pragma unroll
      for (int kj = 0; kj < 5; ++kj) m = fmaxf(m, pc[ki * Ww + kj]);
  }
  out[pid] = m;
}

// Conservative bits-threshold: admit every u whose exact (ocml) value could
// beat `best`. bgap = best - lpmax. Chain with one-sided margins:
//   G3 = bgap - 2^-8  (covers f32 add slop + ocml logf eval error)
//   U_lo <= exp(-exp(-G3)) via +/- 2^-16 relative slop around each __expf
//   key threshold - 64 on the integer conversion.
// Monotone non-decreasing in bgap; stale/looser thr is always sound.
__device__ __forceinline__ uint32_t mkthr(float bgap) {
  float g3 = bgap - 0.00390625f;
  float e1 = __expf(-g3) * 1.0000153f;   // >= exp(-g3)
  float ul = __expf(-e1) * 0.9999847f;   // <= exp(-e1) <= inverse
  int kt = (int)(ul * 8388608.0f) - 64;
  return (kt < 1) ? 0u : ((uint32_t)kt << 9);
}

// LDS threshold table: bin i holds mkthr(-8 + i/32), valid (conservative)
// for any bgap >= its lower edge. Lookup uses bin(bgap) - 1 via the +255
// bias, absorbing fma rounding and guaranteeing a lower-edge (looser) value.
constexpr int NBIN = 640;

// Exact path (rare): bit-identical to the reference/previous passing kernel.
__device__ __forceinline__ void upd(uint32_t bits, float lp, float lpmax,
                                    int cf, float& best, int& bi,
                                    uint32_t& thr, const uint32_t* tab) {
  if (bits < thr) return;                       // level-1 gate: 1 compare
  uint32_t key = bits >> 9;
  float f = __uint_as_float(key | 0x3f800000u) - 1.0f;
  float u = (f == 0.0f) ? 1.17549435e-38f : f;  // max(tiny, f)
  float l1 = logf(u);
  float v = -logf(-l1) + lp;                    // g + lp, exact ocml chain
  if (v > best) {                               // strict >: first-max-wins
    best = v;
    bi = cf;
    float bg = v - lpmax;
    int bin = (int)__builtin_fmaf(bg, 32.0f, 255.0f);  // floor((bg+8)*32)-1
    if (bin < 0) thr = 0u;
    else thr = tab[bin > (NBIN - 1) ? (NBIN - 1) : bin];
  }
}

// One thread per t-PAIR: samples (b,t,x,y) and (b,t+48,x,y) share the lp
// stream, lpmax, and loop overhead; two independent threefry chains give
// 2x ILP on the serial ARX dependency chain.
__global__ __launch_bounds__(256) void k_sample(const float* __restrict__ logp,
                                                const float* __restrict__ lpmaxa,
                                                int* __restrict__ spikes) {
  __shared__ uint32_t thr_tab[NBIN];
  for (int i = threadIdx.x; i < NBIN; i += 256)
    thr_tab[i] = mkthr(__builtin_fmaf((float)i, 0.03125f, -8.0f));
  __syncthreads();

  int tid = blockIdx.x * 256 + threadIdx.x;  // [0, NSAMP/2)
  int y = tid % OWt;
  int x = (tid / OWt) % OHt;
  int t = (tid / NPIX) % 48;
  int b = tid / (NPIX * 48);
  int sid1 = ((b * TT + t) * OHt + x) * OWt + y;
  int sid2 = sid1 + 48 * NPIX;
  uint32_t base1 = (uint32_t)sid1 * 600u + 42u;  // ks1 pre-added
  uint32_t base2 = (uint32_t)sid2 * 600u + 42u;
  const float* lpb = logp + (b * Cc) * (Hh * Ww) + x * Ww + y;
  float lpmax = lpmaxa[(b * OHt + x) * OWt + y];
  float best1 = -1e30f, best2 = -1e30f;
  int bi1 = 0, bi2 = 0;
  uint32_t thr1 = 0u, thr2 = 0u;  // 0 => admit-all (warm-up)
  int cf = 0;
  #pragma unroll 1
  for (int c = 0; c < Cc; ++c) {
    const float* lpc = lpb + c * (Hh * Ww);
    #pragma unroll
    for (int ki = 0; ki < 5; ++ki) {
      #pragma unroll
      for (int kj = 0; kj < 5; ++kj) {
        float lp = lpc[ki * Ww + kj];
        uint32_t bits1 = threefry_0_42_pre(base1 + (uint32_t)cf);
        uint32_t bits2 = threefry_0_42_pre(base2 + (uint32_t)cf);
        upd(bits1, lp, lpmax, cf, best1, bi1, thr1, thr_tab);
        upd(bits2, lp, lpmax, cf, best2, bi2, thr2, thr_tab);
        ++cf;
      }
    }
  }
  spikes[sid1] = bi1;
  spikes[sid2] = bi2;
}

// One wave per pixel, 2 neurons per lane; 96 sequential normalized updates.
__global__ __launch_bounds__(256) void k_recur(
    const int* __restrict__ spikes, const float* __restrict__ weights,
    const float* __restrict__ eps_xy, const float* __restrict__ eps_t,
    const float* __restrict__ eps0p, const float* __restrict__ h_init,
    float* __restrict__ out) {
  int wid = blockIdx.x * 4 + (threadIdx.x >> 6);  // pixel id in [0, 18432)
  int lane = threadIdx.x & 63;
  int y = wid % OWt;
  int x = (wid / OWt) % OHt;
  int b = wid / NPIX;
  float g0 = h_init[lane];
  float g1 = h_init[lane + 64];
  float e0 = eps0p[0];
  const int* sp = spikes + (b * TT) * NPIX + x * OWt + y;
  const float* ex = eps_xy + (x * OWt + y) * 25;
  for (int t = 0; t < TT; ++t) {
    int s = sp[t * NPIX];  // wave-uniform
    const float* wr = weights + s * HN;
    float wg0 = wr[lane] * g0;
    float wg1 = wr[lane + 64] * g1;
    float sum = wg0 + wg1;
    #pragma unroll
    for (int off = 32; off > 0; off >>= 1) sum += __shfl_xor(sum, off, 64);
    float es = ex[s % 25] * (eps_t[t] * e0);  // eps * (et * eps0)
    float factor = es / sum;
    if (!__builtin_isfinite(factor)) factor = 0.0f;  // nan_to_num
    float d = 1.0f + es;
    g0 = (g0 + wg0 * factor) / d;
    g1 = (g1 + wg1 * factor) / d;
  }
  out[((b * HN + lane) * OHt + x) * OWt + y] = g0;
  out[((b * HN + lane + 64) * OHt + x) * OWt + y] = g1;
}

extern "C" void kernel_launch(void* const* d_in, const int* in_sizes, int n_in,
                              void* d_out, int out_size, void* d_ws, size_t ws_size,
                              hipStream_t stream) {
  const float* input   = (const float*)d_in[0];
  const float* eps_xy  = (const float*)d_in[1];
  const float* eps0    = (const float*)d_in[2];
  const float* eps_t   = (const float*)d_in[3];
  const float* weights = (const float*)d_in[4];
  const float* h_init  = (const float*)d_in[5];
  // d_in[6] = number_of_spikes (=96, hardcoded)

  float* logp = (float*)d_ws;                                // 602,112 f32
  int* spikes = (int*)((char*)d_ws + NLOG * sizeof(float));  // 1,769,472 i32
  // lpmax (18432 f32) staged in d_out; k_recur fully overwrites it later.
  float* lpmax = (float*)d_out;

  k_log<<<(NLOG + 255) / 256, 256, 0, stream>>>(input, logp);
  k_lpmax<<<(Bn * NPIX + 255) / 256, 256, 0, stream>>>(logp, lpmax);
  k_sample<<<(NSAMP / 2) / 256, 256, 0, stream>>>(logp, lpmax, spikes);
  k_recur<<<(Bn * NPIX) / 4, 256, 0, stream>>>(spikes, weights, eps_xy, eps_t,
                                               eps0, h_init, (float*)d_out);
}

// Round 4
// 2375.694 us; speedup vs baseline: 1.3065x; 1.0020x over previous
//
#include <hip/hip_runtime.h>
#include <stdint.h>

// Problem constants (fixed by setup_inputs)
constexpr int Bn = 32, Cc = 24, Hh = 28, Ww = 28;
constexpr int OHt = 24, OWt = 24;           // output spatial
constexpr int CF = 600, HN = 128, TT = 96;  // channels-folded, hidden, spikes
constexpr int NPIX = OHt * OWt;             // 576
constexpr int NSAMP = Bn * TT * NPIX;       // 1,769,472
constexpr int NLOG = Bn * Cc * Hh * Ww;     // 602,112
constexpr int NBIN = 640;                   // thr table bins, bgap in [-8, 12)
constexpr int KREC = 24;                    // record slots per sample

// ---- JAX threefry2x32, key(42) -> (0, 42), partitionable counter mode ----
// Caller pre-adds the ks1=42 key injection: pass x1 = counter + 42.
__device__ __forceinline__ uint32_t threefry_0_42_pre(uint32_t x1) {
  const uint32_t ks1 = 42u, ks2 = 0x1BD11BF0u;  // 0x1BD11BDA ^ 0 ^ 42
  uint32_t x0 = x1;                                      // 0 + x1
  x1 = __builtin_rotateleft32(x1, 13) ^ x0;
  x0 += x1; x1 = __builtin_rotateleft32(x1, 15) ^ x0;
  x0 += x1; x1 = __builtin_rotateleft32(x1, 26) ^ x0;
  x0 += x1; x1 = __builtin_rotateleft32(x1,  6) ^ x0;
  x0 += ks1; x1 += ks2 + 1u;
  x0 += x1; x1 = __builtin_rotateleft32(x1, 17) ^ x0;
  x0 += x1; x1 = __builtin_rotateleft32(x1, 29) ^ x0;
  x0 += x1; x1 = __builtin_rotateleft32(x1, 16) ^ x0;
  x0 += x1; x1 = __builtin_rotateleft32(x1, 24) ^ x0;
  x0 += ks2; x1 += 2u;
  x0 += x1; x1 = __builtin_rotateleft32(x1, 13) ^ x0;
  x0 += x1; x1 = __builtin_rotateleft32(x1, 15) ^ x0;
  x0 += x1; x1 = __builtin_rotateleft32(x1, 26) ^ x0;
  x0 += x1; x1 = __builtin_rotateleft32(x1,  6) ^ x0;
  x1 += ks1 + 3u;
  x0 += x1; x1 = __builtin_rotateleft32(x1, 17) ^ x0;
  x0 += x1; x1 = __builtin_rotateleft32(x1, 29) ^ x0;
  x0 += x1; x1 = __builtin_rotateleft32(x1, 16) ^ x0;
  x0 += x1; x1 = __builtin_rotateleft32(x1, 24) ^ x0;
  x0 += ks1; x1 += ks2 + 4u;
  x0 += x1; x1 = __builtin_rotateleft32(x1, 13) ^ x0;
  x0 += x1; x1 = __builtin_rotateleft32(x1, 15) ^ x0;
  x0 += x1; x1 = __builtin_rotateleft32(x1, 26) ^ x0;
  x0 += x1; x1 = __builtin_rotateleft32(x1,  6) ^ x0;
  x0 += ks2; x1 += 5u;
  return x0 ^ x1;
}

__global__ __launch_bounds__(256) void k_log(const float* __restrict__ in,
                                             float* __restrict__ lp) {
  int i = blockIdx.x * 256 + threadIdx.x;
  if (i < NLOG) lp[i] = logf(in[i]);
}

// Conservative bits-threshold: admit every u whose exact (ocml) value could
// beat a comparator b with gap bgap = b - lp. One-sided margin chain:
//   G3 = bgap - 2^-8; U_lo <= inverse via +/-2^-16 expf slop; key -64.
// Monotone non-decreasing in bgap; stale/looser thr is always sound.
__device__ __forceinline__ uint32_t mkthr(float bgap) {
  float g3 = bgap - 0.00390625f;
  float e1 = __expf(-g3) * 1.0000153f;   // >= exp(-g3)
  float ul = __expf(-e1) * 0.9999847f;   // <= exp(-e1) <= inverse
  int kt = (int)(ul * 8388608.0f) - 64;
  return (kt < 1) ? 0u : ((uint32_t)kt << 9);
}

// Exact value (bit-identical to the reference/previous passing kernels).
__device__ __forceinline__ float exact_v(uint32_t bits, float lp) {
  uint32_t key = bits >> 9;
  float f = __uint_as_float(key | 0x3f800000u) - 1.0f;
  float u = (f == 0.0f) ? 1.17549435e-38f : f;  // max(tiny, f)
  float l1 = logf(u);
  return -logf(-l1) + lp;
}

// Phase A record step. bA32 tracks 32*(approx running max)+255 with the
// -ln(ln2) offset folded in (bias 255 + 32*0.36651292 = 266.7284135), so
// t = fma(lp,-32,bA32) = 32*(b_eff - lp + 8) - 1: the "bin-1" biased index
// into thr_tab (lower-edge conservative values) -> slack in [1/32, 2/32],
// >> approx error (~1e-4). Admitted set is a superset of all prefix maxima,
// hence contains the argmax winner.
__device__ __forceinline__ void rec_upd(uint32_t bits, float lp, float& bA32,
                                        int& cnt, uint16_t (*recs)[256],
                                        const uint32_t* __restrict__ tab,
                                        int cf) {
  float t = __builtin_fmaf(lp, -32.0f, bA32);
  t = fminf(fmaxf(t, 0.0f), 639.0f);            // med3 clamp
  uint32_t thr = tab[(int)t];
  if (bits >= thr) {
    uint32_t key = bits >> 9;
    float f = __uint_as_float(key | 0x3f800000u) - 1.0f;
    float u = (f == 0.0f) ? 1.17549435e-38f : f;
    float lg = __log2f(u);                      // < 0 always
    float n = __log2f(-lg);
    float vh = __builtin_fmaf(-0.6931471805599453f, n, lp);  // ~ v - C
    bA32 = fmaxf(bA32, __builtin_fmaf(vh, 32.0f, 266.7284135f));
    int slot = cnt < KREC - 1 ? cnt : KREC - 1; // clamp (overflow -> rescan)
    recs[slot][threadIdx.x] = (uint16_t)cf;
    ++cnt;
  }
}

// Phase B: exact first-max-wins over the recorded superset (cf ascending),
// or full exact rescan on the rare overflow.
__device__ __forceinline__ int resolve(int cnt, const uint16_t (*recs)[256],
                                       uint32_t base,
                                       const float* __restrict__ lpb) {
  float best = -1e30f;
  int bi = 0;
  if (cnt <= KREC) {
    for (int j = 0; j < cnt; ++j) {
      int cf = recs[j][threadIdx.x];
      int c = cf / 25;
      int r = cf - c * 25;
      int ki = r / 5;
      int kj = r - ki * 5;
      float lp = lpb[c * (Hh * Ww) + ki * Ww + kj];
      float v = exact_v(threefry_0_42_pre(base + (uint32_t)cf), lp);
      if (v > best) { best = v; bi = cf; }      // strict >: first-max-wins
    }
  } else {
    int cf = 0;
    for (int c = 0; c < Cc; ++c) {
      const float* lpc = lpb + c * (Hh * Ww);
      for (int ki = 0; ki < 5; ++ki)
        for (int kj = 0; kj < 5; ++kj) {
          float v = exact_v(threefry_0_42_pre(base + (uint32_t)cf),
                            lpc[ki * Ww + kj]);
          if (v > best) { best = v; bi = cf; }
          ++cf;
        }
    }
  }
  return bi;
}

// One thread per t-PAIR: samples (b,t,x,y) and (b,t+48,x,y). Phase A has no
// ocml logf at all: threefry + 1-lookup gate + tiny masked record block.
__global__ __launch_bounds__(256) void k_sample(const float* __restrict__ logp,
                                                int* __restrict__ spikes) {
  __shared__ uint32_t thr_tab[NBIN];
  __shared__ uint16_t rec[2][KREC][256];
  for (int i = threadIdx.x; i < NBIN; i += 256)
    thr_tab[i] = mkthr(__builtin_fmaf((float)i, 0.03125f, -8.0f));
  __syncthreads();

  int tid = blockIdx.x * 256 + threadIdx.x;  // [0, NSAMP/2)
  int y = tid % OWt;
  int x = (tid / OWt) % OHt;
  int t = (tid / NPIX) % 48;
  int b = tid / (NPIX * 48);
  int sid1 = ((b * TT + t) * OHt + x) * OWt + y;
  int sid2 = sid1 + 48 * NPIX;
  uint32_t base1 = (uint32_t)sid1 * 600u + 42u;  // ks1 pre-added
  uint32_t base2 = (uint32_t)sid2 * 600u + 42u;
  const float* lpb = logp + (b * Cc) * (Hh * Ww) + x * Ww + y;
  float bA1 = -3.0e38f, bA2 = -3.0e38f;  // -> t clamps to 0 -> thr 0: admit
  int cnt1 = 0, cnt2 = 0;
  int cf = 0;
  #pragma unroll 1
  for (int c = 0; c < Cc; ++c) {
    const float* lpc = lpb + c * (Hh * Ww);
    #pragma unroll 1
    for (int ki = 0; ki < 5; ++ki) {
      #pragma unroll
      for (int kj = 0; kj < 5; ++kj) {
        float lp = lpc[ki * Ww + kj];
        uint32_t bits1 = threefry_0_42_pre(base1 + (uint32_t)cf);
        uint32_t bits2 = threefry_0_42_pre(base2 + (uint32_t)cf);
        rec_upd(bits1, lp, bA1, cnt1, rec[0], thr_tab, cf);
        rec_upd(bits2, lp, bA2, cnt2, rec[1], thr_tab, cf);
        ++cf;
      }
    }
  }
  spikes[sid1] = resolve(cnt1, rec[0], base1, lpb);
  spikes[sid2] = resolve(cnt2, rec[1], base2, lpb);
}

// One wave per pixel, 2 neurons per lane; 96 sequential normalized updates.
__global__ __launch_bounds__(256) void k_recur(
    const int* __restrict__ spikes, const float* __restrict__ weights,
    const float* __restrict__ eps_xy, const float* __restrict__ eps_t,
    const float* __restrict__ eps0p, const float* __restrict__ h_init,
    float* __restrict__ out) {
  int wid = blockIdx.x * 4 + (threadIdx.x >> 6);  // pixel id in [0, 18432)
  int lane = threadIdx.x & 63;
  int y = wid % OWt;
  int x = (wid / OWt) % OHt;
  int b = wid / NPIX;
  float g0 = h_init[lane];
  float g1 = h_init[lane + 64];
  float e0 = eps0p[0];
  const int* sp = spikes + (b * TT) * NPIX + x * OWt + y;
  const float* ex = eps_xy + (x * OWt + y) * 25;
  for (int t = 0; t < TT; ++t) {
    int s = sp[t * NPIX];  // wave-uniform
    const float* wr = weights + s * HN;
    float wg0 = wr[lane] * g0;
    float wg1 = wr[lane + 64] * g1;
    float sum = wg0 + wg1;
    #pragma unroll
    for (int off = 32; off > 0; off >>= 1) sum += __shfl_xor(sum, off, 64);
    float es = ex[s % 25] * (eps_t[t] * e0);  // eps * (et * eps0)
    float factor = es / sum;
    if (!__builtin_isfinite(factor)) factor = 0.0f;  // nan_to_num
    float d = 1.0f + es;
    g0 = (g0 + wg0 * factor) / d;
    g1 = (g1 + wg1 * factor) / d;
  }
  out[((b * HN + lane) * OHt + x) * OWt + y] = g0;
  out[((b * HN + lane + 64) * OHt + x) * OWt + y] = g1;
}

extern "C" void kernel_launch(void* const* d_in, const int* in_sizes, int n_in,
                              void* d_out, int out_size, void* d_ws, size_t ws_size,
                              hipStream_t stream) {
  const float* input   = (const float*)d_in[0];
  const float* eps_xy  = (const float*)d_in[1];
  const float* eps0    = (const float*)d_in[2];
  const float* eps_t   = (const float*)d_in[3];
  const float* weights = (const float*)d_in[4];
  const float* h_init  = (const float*)d_in[5];
  // d_in[6] = number_of_spikes (=96, hardcoded)

  float* logp = (float*)d_ws;                                // 602,112 f32
  int* spikes = (int*)((char*)d_ws + NLOG * sizeof(float));  // 1,769,472 i32

  k_log<<<(NLOG + 255) / 256, 256, 0, stream>>>(input, logp);
  k_sample<<<(NSAMP / 2) / 256, 256, 0, stream>>>(logp, spikes);
  k_recur<<<(Bn * NPIX) / 4, 256, 0, stream>>>(spikes, weights, eps_xy, eps_t,
                                               eps0, h_init, (float*)d_out);
}